// Round 2
// baseline (161.257 us; speedup 1.0000x reference)
//
#include <hip/hip_runtime.h>

// QuantileLoss: mean over (N,5) loss matrix, fused single-kernel version.
//   cols 0-2: (preds[:,0:3] - target[:,0:3])^2
//   col 3: lower = p_lo>p_mid ? 1000 : (p_lo > 0.95*t ? 0 : (p_lo-t)^2)
//   col 4: upper = p_hi<p_mid ? 1000 : (p_hi < 1.05*t ? 0 : (p_hi-t)^2)
// preds (N,6) f32, target (N,4) f32, out: 1 f32 scalar.
//
// Last-block-done reduction: each block writes a float partial to d_ws,
// bumps a device-scope counter; the last block re-reduces all partials in
// double in a FIXED order (deterministic) and writes out[0].

#define QL_BLOCKS 2048
#define QL_THREADS 256

__global__ __launch_bounds__(QL_THREADS)
void ql_fused(const float* __restrict__ preds,
              const float* __restrict__ target,
              float* __restrict__ out,
              float* __restrict__ partial,
              unsigned int* __restrict__ counter,
              int npairs, double inv_count) {
    const float PEN = 1000.0f;
    int tid = blockIdx.x * blockDim.x + threadIdx.x;
    int stride = gridDim.x * blockDim.x;
    float sum = 0.0f;

    for (int i = tid; i < npairs; i += stride) {
        // 2 preds rows = 3 x float4 (48B, 16-aligned), 2 target rows = 2 x float4
        const float4* pp = reinterpret_cast<const float4*>(preds + (size_t)i * 12);
        const float4* tt = reinterpret_cast<const float4*>(target + (size_t)i * 8);
        float4 a = pp[0];
        float4 b = pp[1];
        float4 c = pp[2];
        float4 ta = tt[0];
        float4 tb = tt[1];

        // row 0: preds = a.x a.y a.z a.w b.x b.y ; target = ta
        {
            float d0 = a.x - ta.x, d1 = a.y - ta.y, d2 = a.z - ta.z;
            sum += d0 * d0 + d1 * d1 + d2 * d2;
            float pm = a.w, pl = b.x, ph = b.y, t = ta.w;
            float dl = pl - t, du = ph - t;
            float lower = (pl > pm) ? PEN : ((pl > t * 0.95f) ? 0.0f : dl * dl);
            float upper = (ph < pm) ? PEN : ((ph < t * 1.05f) ? 0.0f : du * du);
            sum += lower + upper;
        }
        // row 1: preds = b.z b.w c.x c.y c.z c.w ; target = tb
        {
            float d0 = b.z - tb.x, d1 = b.w - tb.y, d2 = c.x - tb.z;
            sum += d0 * d0 + d1 * d1 + d2 * d2;
            float pm = c.y, pl = c.z, ph = c.w, t = tb.w;
            float dl = pl - t, du = ph - t;
            float lower = (pl > pm) ? PEN : ((pl > t * 0.95f) ? 0.0f : dl * dl);
            float upper = (ph < pm) ? PEN : ((ph < t * 1.05f) ? 0.0f : du * du);
            sum += lower + upper;
        }
    }

    // wave64 shuffle reduction
    #pragma unroll
    for (int off = 32; off > 0; off >>= 1)
        sum += __shfl_down(sum, off, 64);

    __shared__ float wsum[QL_THREADS / 64];
    __shared__ bool is_last;
    int lane = threadIdx.x & 63;
    int wid = threadIdx.x >> 6;
    if (lane == 0) wsum[wid] = sum;
    __syncthreads();
    if (threadIdx.x == 0) {
        float s = 0.0f;
        #pragma unroll
        for (int w = 0; w < QL_THREADS / 64; ++w) s += wsum[w];
        partial[blockIdx.x] = s;
        __threadfence();                       // release: partial visible device-wide
        unsigned int prev = atomicAdd(counter, 1u);
        is_last = (prev == gridDim.x - 1);
    }
    __syncthreads();

    if (is_last) {
        __threadfence();                       // acquire: see all partials
        volatile const float* vp = partial;
        double s = 0.0;
        for (int i = threadIdx.x; i < QL_BLOCKS; i += QL_THREADS)
            s += (double)vp[i];

        #pragma unroll
        for (int off = 32; off > 0; off >>= 1)
            s += __shfl_down(s, off, 64);

        __shared__ double dsum[QL_THREADS / 64];
        if (lane == 0) dsum[wid] = s;
        __syncthreads();
        if (threadIdx.x == 0) {
            double t = 0.0;
            #pragma unroll
            for (int w = 0; w < QL_THREADS / 64; ++w) t += dsum[w];
            out[0] = (float)(t * inv_count);
        }
    }
}

extern "C" void kernel_launch(void* const* d_in, const int* in_sizes, int n_in,
                              void* d_out, int out_size, void* d_ws, size_t ws_size,
                              hipStream_t stream) {
    const float* preds  = (const float*)d_in[0];
    const float* target = (const float*)d_in[1];
    float* out = (float*)d_out;

    // d_ws layout: [0,4)  counter (uint), [256, 256 + QL_BLOCKS*4) partials
    unsigned int* counter = (unsigned int*)d_ws;
    float* partial = (float*)((char*)d_ws + 256);

    int N = in_sizes[0] / 6;   // rows
    int npairs = N / 2;        // N = 8388608 is even

    // counter must be zero at the start of every call (d_ws is poisoned once,
    // never restored between replays)
    hipMemsetAsync(counter, 0, sizeof(unsigned int), stream);

    double inv_count = 1.0 / ((double)N * 5.0);
    ql_fused<<<QL_BLOCKS, QL_THREADS, 0, stream>>>(preds, target, out, partial,
                                                   counter, npairs, inv_count);
}

// Round 3
// 69.834 us; speedup vs baseline: 2.3092x; 2.3092x over previous
//
#include <hip/hip_runtime.h>

// QuantileLoss: mean over (N,5) loss matrix, fused single-kernel version.
//   cols 0-2: (preds[:,0:3] - target[:,0:3])^2
//   col 3: lower = p_lo>p_mid ? 1000 : (p_lo > 0.95*t ? 0 : (p_lo-t)^2)
//   col 4: upper = p_hi<p_mid ? 1000 : (p_hi < 1.05*t ? 0 : (p_hi-t)^2)
// preds (N,6) f32, target (N,4) f32, out: 1 f32 scalar.
//
// Last-block-done reduction WITHOUT threadfence (R2's __threadfence() emitted
// a full L2 writeback per block -> 2.7x regression). Instead each block
// publishes its partial with a device-scope atomicExch (performed at the
// coherent point), waits vmcnt(0), then bumps the counter atomically. The
// last block reads partials with agent-scope relaxed atomic loads and
// reduces in double in a FIXED order (bit-deterministic output).

#define QL_BLOCKS 2048
#define QL_THREADS 256

__global__ __launch_bounds__(QL_THREADS)
void ql_fused(const float* __restrict__ preds,
              const float* __restrict__ target,
              float* __restrict__ out,
              float* __restrict__ partial,
              unsigned int* __restrict__ counter,
              int npairs, double inv_count) {
    const float PEN = 1000.0f;
    int tid = blockIdx.x * blockDim.x + threadIdx.x;
    int stride = gridDim.x * blockDim.x;
    float sum = 0.0f;

    for (int i = tid; i < npairs; i += stride) {
        // 2 preds rows = 3 x float4 (48B, 16-aligned), 2 target rows = 2 x float4
        const float4* pp = reinterpret_cast<const float4*>(preds + (size_t)i * 12);
        const float4* tt = reinterpret_cast<const float4*>(target + (size_t)i * 8);
        float4 a = pp[0];
        float4 b = pp[1];
        float4 c = pp[2];
        float4 ta = tt[0];
        float4 tb = tt[1];

        // row 0: preds = a.x a.y a.z a.w b.x b.y ; target = ta
        {
            float d0 = a.x - ta.x, d1 = a.y - ta.y, d2 = a.z - ta.z;
            sum += d0 * d0 + d1 * d1 + d2 * d2;
            float pm = a.w, pl = b.x, ph = b.y, t = ta.w;
            float dl = pl - t, du = ph - t;
            float lower = (pl > pm) ? PEN : ((pl > t * 0.95f) ? 0.0f : dl * dl);
            float upper = (ph < pm) ? PEN : ((ph < t * 1.05f) ? 0.0f : du * du);
            sum += lower + upper;
        }
        // row 1: preds = b.z b.w c.x c.y c.z c.w ; target = tb
        {
            float d0 = b.z - tb.x, d1 = b.w - tb.y, d2 = c.x - tb.z;
            sum += d0 * d0 + d1 * d1 + d2 * d2;
            float pm = c.y, pl = c.z, ph = c.w, t = tb.w;
            float dl = pl - t, du = ph - t;
            float lower = (pl > pm) ? PEN : ((pl > t * 0.95f) ? 0.0f : dl * dl);
            float upper = (ph < pm) ? PEN : ((ph < t * 1.05f) ? 0.0f : du * du);
            sum += lower + upper;
        }
    }

    // wave64 shuffle reduction
    #pragma unroll
    for (int off = 32; off > 0; off >>= 1)
        sum += __shfl_down(sum, off, 64);

    __shared__ float wsum[QL_THREADS / 64];
    __shared__ bool is_last;
    int lane = threadIdx.x & 63;
    int wid = threadIdx.x >> 6;
    if (lane == 0) wsum[wid] = sum;
    __syncthreads();
    if (threadIdx.x == 0) {
        float s = 0.0f;
        #pragma unroll
        for (int w = 0; w < QL_THREADS / 64; ++w) s += wsum[w];
        // Publish at the coherent point (device-scope atomic store) — no
        // L2-writeback fence needed.
        atomicExch(&partial[blockIdx.x], s);
        // Order: the exch must complete at the coherent point before the
        // counter bump issues.
        asm volatile("s_waitcnt vmcnt(0)" ::: "memory");
        unsigned int prev = atomicAdd(counter, 1u);
        is_last = (prev == gridDim.x - 1);
    }
    __syncthreads();

    if (is_last) {
        asm volatile("" ::: "memory");  // no hoisting of loads above the check
        double s = 0.0;
        for (int i = threadIdx.x; i < QL_BLOCKS; i += QL_THREADS) {
            float v = __hip_atomic_load(&partial[i], __ATOMIC_RELAXED,
                                        __HIP_MEMORY_SCOPE_AGENT);
            s += (double)v;
        }

        #pragma unroll
        for (int off = 32; off > 0; off >>= 1)
            s += __shfl_down(s, off, 64);

        __shared__ double dsum[QL_THREADS / 64];
        if (lane == 0) dsum[wid] = s;
        __syncthreads();
        if (threadIdx.x == 0) {
            double t = 0.0;
            #pragma unroll
            for (int w = 0; w < QL_THREADS / 64; ++w) t += dsum[w];
            out[0] = (float)(t * inv_count);
        }
    }
}

extern "C" void kernel_launch(void* const* d_in, const int* in_sizes, int n_in,
                              void* d_out, int out_size, void* d_ws, size_t ws_size,
                              hipStream_t stream) {
    const float* preds  = (const float*)d_in[0];
    const float* target = (const float*)d_in[1];
    float* out = (float*)d_out;

    // d_ws layout: [0,4) counter (uint), [256, 256 + QL_BLOCKS*4) partials
    unsigned int* counter = (unsigned int*)d_ws;
    float* partial = (float*)((char*)d_ws + 256);

    int N = in_sizes[0] / 6;   // rows
    int npairs = N / 2;        // N = 8388608 is even

    // counter must be zero at the start of every call (d_ws is poisoned once,
    // never restored between replays)
    hipMemsetAsync(counter, 0, sizeof(unsigned int), stream);

    double inv_count = 1.0 / ((double)N * 5.0);
    ql_fused<<<QL_BLOCKS, QL_THREADS, 0, stream>>>(preds, target, out, partial,
                                                   counter, npairs, inv_count);
}

// Round 5
// 64.567 us; speedup vs baseline: 2.4975x; 1.0816x over previous
//
#include <hip/hip_runtime.h>

// QuantileLoss: mean over (N,5) loss matrix, fused single-kernel version.
//   cols 0-2: (preds[:,0:3] - target[:,0:3])^2
//   col 3: lower = p_lo>p_mid ? 1000 : (p_lo > 0.95*t ? 0 : (p_lo-t)^2)
//   col 4: upper = p_hi<p_mid ? 1000 : (p_hi < 1.05*t ? 0 : (p_hi-t)^2)
// preds (N,6) f32, target (N,4) f32, out: 1 f32 scalar.
//
// Lessons ledger:
//  - R2: __threadfence() = full L2 writeback per block -> 2.7x regression.
//    Publish partials with device-scope atomics instead (no fence).
//  - R3: 2048 atomicAdds on ONE counter serialize (~5ns/op => ~10us tail).
//  - R4: modular boundary detection fires EARLY from poisoned counters
//    (crossing can happen at arrival k<32) -> stale partials -> wrong sum.
//    => counters MUST start at 0: one tiny hipMemsetAsync per call.
//  - R5: exact-count two-level tree over zeroed counters. 64 sub-counters
//    on separate 64B lines (32 arrivals each, drain in parallel), group
//    completer (p1==31) bumps main; winner (p2==63) re-reduces all 2048
//    partials in double in FIXED order -> bit-deterministic output.

#define QL_BLOCKS 2048
#define QL_THREADS 256
#define QL_NSUB 64            // sub-counters; 2048/64 = 32 arrivals each

__global__ __launch_bounds__(QL_THREADS)
void ql_fused(const float* __restrict__ preds,
              const float* __restrict__ target,
              float* __restrict__ out,
              unsigned int* __restrict__ ws_u32,   // counters region (zeroed)
              float* __restrict__ partial,
              int npairs, double inv_count) {
    const float PEN = 1000.0f;
    int tid = blockIdx.x * blockDim.x + threadIdx.x;
    int stride = gridDim.x * blockDim.x;
    float sum = 0.0f;

    for (int i = tid; i < npairs; i += stride) {
        // 2 preds rows = 3 x float4 (48B, 16-aligned), 2 target rows = 2 x float4
        const float4* pp = reinterpret_cast<const float4*>(preds + (size_t)i * 12);
        const float4* tt = reinterpret_cast<const float4*>(target + (size_t)i * 8);
        float4 a = pp[0];
        float4 b = pp[1];
        float4 c = pp[2];
        float4 ta = tt[0];
        float4 tb = tt[1];

        // row 0: preds = a.x a.y a.z a.w b.x b.y ; target = ta
        {
            float d0 = a.x - ta.x, d1 = a.y - ta.y, d2 = a.z - ta.z;
            sum += d0 * d0 + d1 * d1 + d2 * d2;
            float pm = a.w, pl = b.x, ph = b.y, t = ta.w;
            float dl = pl - t, du = ph - t;
            float lower = (pl > pm) ? PEN : ((pl > t * 0.95f) ? 0.0f : dl * dl);
            float upper = (ph < pm) ? PEN : ((ph < t * 1.05f) ? 0.0f : du * du);
            sum += lower + upper;
        }
        // row 1: preds = b.z b.w c.x c.y c.z c.w ; target = tb
        {
            float d0 = b.z - tb.x, d1 = b.w - tb.y, d2 = c.x - tb.z;
            sum += d0 * d0 + d1 * d1 + d2 * d2;
            float pm = c.y, pl = c.z, ph = c.w, t = tb.w;
            float dl = pl - t, du = ph - t;
            float lower = (pl > pm) ? PEN : ((pl > t * 0.95f) ? 0.0f : dl * dl);
            float upper = (ph < pm) ? PEN : ((ph < t * 1.05f) ? 0.0f : du * du);
            sum += lower + upper;
        }
    }

    // wave64 shuffle reduction
    #pragma unroll
    for (int off = 32; off > 0; off >>= 1)
        sum += __shfl_down(sum, off, 64);

    __shared__ float wsum[QL_THREADS / 64];
    __shared__ bool is_last;
    int lane = threadIdx.x & 63;
    int wid = threadIdx.x >> 6;
    if (lane == 0) wsum[wid] = sum;
    __syncthreads();
    if (threadIdx.x == 0) {
        float s = 0.0f;
        #pragma unroll
        for (int w = 0; w < QL_THREADS / 64; ++w) s += wsum[w];

        // Publish partial at the coherent point (device-scope atomic store).
        atomicExch(&partial[blockIdx.x], s);
        // Exch must be performed before any counter bump issues.
        asm volatile("s_waitcnt vmcnt(0)" ::: "memory");

        bool winner = false;
        // Level 1: 64 padded sub-counters (own 64B lines), 32 arrivals each.
        unsigned int g = blockIdx.x & (QL_NSUB - 1);
        unsigned int* sub = ws_u32 + 256 + g * 16;   // byte 1024 + g*64
        unsigned int p1 = atomicAdd(sub, 1u);        // ret-val dep = ordered
        if (p1 == 31u) {                             // exact: 32nd arrival
            // Level 2: main counter, 64 arrivals.
            unsigned int p2 = atomicAdd(ws_u32, 1u);
            winner = (p2 == 63u);                    // exact: 64th arrival
        }
        is_last = winner;
    }
    __syncthreads();

    if (is_last) {
        // All 2048 sub-adds acked => all 2048 exchs at coherent point.
        double s = 0.0;
        for (int i = threadIdx.x; i < QL_BLOCKS; i += QL_THREADS) {
            float v = __hip_atomic_load(&partial[i], __ATOMIC_RELAXED,
                                        __HIP_MEMORY_SCOPE_AGENT);
            s += (double)v;
        }

        #pragma unroll
        for (int off = 32; off > 0; off >>= 1)
            s += __shfl_down(s, off, 64);

        __shared__ double dsum[QL_THREADS / 64];
        if (lane == 0) dsum[wid] = s;
        __syncthreads();
        if (threadIdx.x == 0) {
            double t = 0.0;
            #pragma unroll
            for (int w = 0; w < QL_THREADS / 64; ++w) t += dsum[w];
            out[0] = (float)(t * inv_count);
        }
    }
}

extern "C" void kernel_launch(void* const* d_in, const int* in_sizes, int n_in,
                              void* d_out, int out_size, void* d_ws, size_t ws_size,
                              hipStream_t stream) {
    const float* preds  = (const float*)d_in[0];
    const float* target = (const float*)d_in[1];
    float* out = (float*)d_out;

    // d_ws layout:
    //   [0,4)            main counter (uint)
    //   [1024, 5120)     64 sub-counters, 64B apart
    //   [8192, 8192+8KB) 2048 float partials
    unsigned int* ws_u32 = (unsigned int*)d_ws;
    float* partial = (float*)((char*)d_ws + 8192);

    int N = in_sizes[0] / 6;   // rows
    int npairs = N / 2;        // N = 8388608 is even

    // Counters must be EXACTLY zero at the start of every call (R4 lesson:
    // modular detection from poisoned values fires early). 5KB memset.
    hipMemsetAsync(d_ws, 0, 5120, stream);

    double inv_count = 1.0 / ((double)N * 5.0);
    ql_fused<<<QL_BLOCKS, QL_THREADS, 0, stream>>>(preds, target, out, ws_u32,
                                                   partial, npairs, inv_count);
}

// Round 6
// 59.541 us; speedup vs baseline: 2.7083x; 1.0844x over previous
//
#include <hip/hip_runtime.h>

// QuantileLoss: mean over (N,5) loss matrix.
//   cols 0-2: (preds[:,0:3] - target[:,0:3])^2
//   col 3: lower = p_lo>p_mid ? 1000 : (p_lo > 0.95*t ? 0 : (p_lo-t)^2)
//   col 4: upper = p_hi<p_mid ? 1000 : (p_hi < 1.05*t ? 0 : (p_hi-t)^2)
// preds (N,6) f32, target (N,4) f32, out: 1 f32 scalar.
//
// Lessons ledger:
//  - R2: __threadfence() = full-L2-writeback per block -> 2.7x regression.
//  - R3: 2048 atomicAdds on ONE counter serialize (~10us tail).
//  - R4: modular counter detection fires early from poisoned values.
//  - R5: fused + counter-tree + 4B memset = 64.6us > R1's 58.8us.
//    Fusion family loses to plain two-kernel in graph replay. REVERTED.
//  - R6: R1 structure + 2x unroll / dual accumulators. R3/R5 counters show
//    FETCH ~165MB (half of input L3-resident across replays) => HBM not
//    saturated (~3.1 TB/s); consumption 6.2 TB/s suggests MLP-bound.
//    VGPR=16 = almost nothing in flight. Issue 10 float4 loads per iter.

#define QL_BLOCKS 2048
#define QL_THREADS 256

__global__ __launch_bounds__(QL_THREADS)
void ql_partial(const float* __restrict__ preds,
                const float* __restrict__ target,
                float* __restrict__ partial,
                int npairs) {
    const float PEN = 1000.0f;
    int tid = blockIdx.x * blockDim.x + threadIdx.x;
    int stride = gridDim.x * blockDim.x;
    float sum0 = 0.0f, sum1 = 0.0f;

    int i = tid;
    // 2x unrolled: 10 independent float4 loads in flight before compute.
    for (; i + stride < npairs; i += 2 * stride) {
        int j = i + stride;
        const float4* pp0 = reinterpret_cast<const float4*>(preds + (size_t)i * 12);
        const float4* tt0 = reinterpret_cast<const float4*>(target + (size_t)i * 8);
        const float4* pp1 = reinterpret_cast<const float4*>(preds + (size_t)j * 12);
        const float4* tt1 = reinterpret_cast<const float4*>(target + (size_t)j * 8);
        float4 a0 = pp0[0], b0 = pp0[1], c0 = pp0[2];
        float4 ta0 = tt0[0], tb0 = tt0[1];
        float4 a1 = pp1[0], b1 = pp1[1], c1 = pp1[2];
        float4 ta1 = tt1[0], tb1 = tt1[1];

        // ---- pair 0, row 0
        {
            float d0 = a0.x - ta0.x, d1 = a0.y - ta0.y, d2 = a0.z - ta0.z;
            sum0 += d0 * d0 + d1 * d1 + d2 * d2;
            float pm = a0.w, pl = b0.x, ph = b0.y, t = ta0.w;
            float dl = pl - t, du = ph - t;
            sum0 += ((pl > pm) ? PEN : ((pl > t * 0.95f) ? 0.0f : dl * dl))
                  + ((ph < pm) ? PEN : ((ph < t * 1.05f) ? 0.0f : du * du));
        }
        // ---- pair 0, row 1
        {
            float d0 = b0.z - tb0.x, d1 = b0.w - tb0.y, d2 = c0.x - tb0.z;
            sum0 += d0 * d0 + d1 * d1 + d2 * d2;
            float pm = c0.y, pl = c0.z, ph = c0.w, t = tb0.w;
            float dl = pl - t, du = ph - t;
            sum0 += ((pl > pm) ? PEN : ((pl > t * 0.95f) ? 0.0f : dl * dl))
                  + ((ph < pm) ? PEN : ((ph < t * 1.05f) ? 0.0f : du * du));
        }
        // ---- pair 1, row 0
        {
            float d0 = a1.x - ta1.x, d1 = a1.y - ta1.y, d2 = a1.z - ta1.z;
            sum1 += d0 * d0 + d1 * d1 + d2 * d2;
            float pm = a1.w, pl = b1.x, ph = b1.y, t = ta1.w;
            float dl = pl - t, du = ph - t;
            sum1 += ((pl > pm) ? PEN : ((pl > t * 0.95f) ? 0.0f : dl * dl))
                  + ((ph < pm) ? PEN : ((ph < t * 1.05f) ? 0.0f : du * du));
        }
        // ---- pair 1, row 1
        {
            float d0 = b1.z - tb1.x, d1 = b1.w - tb1.y, d2 = c1.x - tb1.z;
            sum1 += d0 * d0 + d1 * d1 + d2 * d2;
            float pm = c1.y, pl = c1.z, ph = c1.w, t = tb1.w;
            float dl = pl - t, du = ph - t;
            sum1 += ((pl > pm) ? PEN : ((pl > t * 0.95f) ? 0.0f : dl * dl))
                  + ((ph < pm) ? PEN : ((ph < t * 1.05f) ? 0.0f : du * du));
        }
    }
    // tail (not taken for N=8388608 with 2048x256, kept for generality)
    for (; i < npairs; i += stride) {
        const float4* pp = reinterpret_cast<const float4*>(preds + (size_t)i * 12);
        const float4* tt = reinterpret_cast<const float4*>(target + (size_t)i * 8);
        float4 a = pp[0], b = pp[1], c = pp[2];
        float4 ta = tt[0], tb = tt[1];
        {
            float d0 = a.x - ta.x, d1 = a.y - ta.y, d2 = a.z - ta.z;
            sum0 += d0 * d0 + d1 * d1 + d2 * d2;
            float pm = a.w, pl = b.x, ph = b.y, t = ta.w;
            float dl = pl - t, du = ph - t;
            sum0 += ((pl > pm) ? PEN : ((pl > t * 0.95f) ? 0.0f : dl * dl))
                  + ((ph < pm) ? PEN : ((ph < t * 1.05f) ? 0.0f : du * du));
        }
        {
            float d0 = b.z - tb.x, d1 = b.w - tb.y, d2 = c.x - tb.z;
            sum0 += d0 * d0 + d1 * d1 + d2 * d2;
            float pm = c.y, pl = c.z, ph = c.w, t = tb.w;
            float dl = pl - t, du = ph - t;
            sum0 += ((pl > pm) ? PEN : ((pl > t * 0.95f) ? 0.0f : dl * dl))
                  + ((ph < pm) ? PEN : ((ph < t * 1.05f) ? 0.0f : du * du));
        }
    }

    float sum = sum0 + sum1;

    // wave64 shuffle reduction
    #pragma unroll
    for (int off = 32; off > 0; off >>= 1)
        sum += __shfl_down(sum, off, 64);

    __shared__ float wsum[QL_THREADS / 64];
    int lane = threadIdx.x & 63;
    int wid = threadIdx.x >> 6;
    if (lane == 0) wsum[wid] = sum;
    __syncthreads();
    if (threadIdx.x == 0) {
        float s = 0.0f;
        #pragma unroll
        for (int w = 0; w < QL_THREADS / 64; ++w) s += wsum[w];
        partial[blockIdx.x] = s;
    }
}

__global__ __launch_bounds__(QL_THREADS)
void ql_final(const float* __restrict__ partial,
              float* __restrict__ out,
              int n, double inv_count) {
    double s = 0.0;
    for (int i = threadIdx.x; i < n; i += blockDim.x)
        s += (double)partial[i];

    #pragma unroll
    for (int off = 32; off > 0; off >>= 1)
        s += __shfl_down(s, off, 64);

    __shared__ double wsum[QL_THREADS / 64];
    int lane = threadIdx.x & 63;
    int wid = threadIdx.x >> 6;
    if (lane == 0) wsum[wid] = s;
    __syncthreads();
    if (threadIdx.x == 0) {
        double t = 0.0;
        #pragma unroll
        for (int w = 0; w < QL_THREADS / 64; ++w) t += wsum[w];
        out[0] = (float)(t * inv_count);
    }
}

extern "C" void kernel_launch(void* const* d_in, const int* in_sizes, int n_in,
                              void* d_out, int out_size, void* d_ws, size_t ws_size,
                              hipStream_t stream) {
    const float* preds  = (const float*)d_in[0];
    const float* target = (const float*)d_in[1];
    float* out = (float*)d_out;
    float* partial = (float*)d_ws;   // QL_BLOCKS floats

    int N = in_sizes[0] / 6;         // rows
    int npairs = N / 2;              // N = 8388608 is even

    ql_partial<<<QL_BLOCKS, QL_THREADS, 0, stream>>>(preds, target, partial, npairs);

    double inv_count = 1.0 / ((double)N * 5.0);
    ql_final<<<1, QL_THREADS, 0, stream>>>(partial, out, QL_BLOCKS, inv_count);
}